// Round 4
// baseline (159.881 us; speedup 1.0000x reference)
//
#include <hip/hip_runtime.h>
#include <hip/hip_bf16.h>
#include <hip/hip_fp16.h>
#include <stdint.h>
#include <math.h>

#define NNODES 100000
#define HID 128
#define NEDGES 1000000
#define NEBLOCKS 15625  // edge blocks: 15625 * 4 waves * 16 edges = 1,000,000

typedef __attribute__((ext_vector_type(4))) float floatx4;
typedef _Float16 f16x2 __attribute__((ext_vector_type(2)));
typedef _Float16 f16x4 __attribute__((ext_vector_type(4)));
typedef _Float16 f16x8 __attribute__((ext_vector_type(8)));

// ---------------- Kernel 0: pack B = [W1_top | W1_bot] into MFMA fragment
// order, f16. Fragment: B[k=(lane>>4)*8+j][n=lane&15],
// element base ((ct*4+ks)*64+lane)*8, ct=0..15 (16-col tiles), ks=0..3.
// Also zeroes the 64 edge-sum accumulator slots (runs first each iteration).
__global__ __launch_bounds__(256) void pack_b_kernel(
    const float* __restrict__ W1, _Float16* __restrict__ Bf,
    float* __restrict__ accum) {
  if (blockIdx.x == 0 && threadIdx.x < 64) accum[threadIdx.x * 16] = 0.f;
  const int t = blockIdx.x * 256 + threadIdx.x;  // 0..4095
  const int lane = t & 63;
  const int ks = (t >> 6) & 3;
  const int ct = t >> 8;
  const int n = ct * 16 + (lane & 15);
  const int kb = ks * 32 + ((lane >> 4) * 8);
  f16x8 h;
#pragma unroll
  for (int j = 0; j < 8; ++j) {
    const int k = kb + j;
    const float v = (n < HID) ? W1[(size_t)k * HID + n]
                              : W1[(size_t)(HID + k) * HID + (n - HID)];
    h[j] = (_Float16)v;
  }
  *(f16x8*)(Bf + (size_t)t * 8) = h;
}

// ---------------- Kernel 1: node projection via single-pass f16 MFMA -------
// Block: 64 rows x 256 cols. Staging: fully-coalesced flat copy (nt loads:
// emb is dead after this read; keep it out of L2 so P writes stay resident
// for the edge kernel), in-register fp32->f16, LDS As[row][k] stride 136
// halfs. One barrier, K-loop: A via ds_read_b128, B frags from L2-hot packed
// global, 64 MFMA/wave. Co aliases As for the epilogue. Epilogue quantizes
// each 128-ch half-row to biased uint8 with a per-half linear scale
// (max|v|/127), storing P (1 B/ch) and scalesInv[node][half].
__global__ __launch_bounds__(256) void project_kernel(
    const float* __restrict__ emb, const _Float16* __restrict__ Bf,
    uint8_t* __restrict__ P, float* __restrict__ scalesInv) {
  __shared__ __align__(16) char smem[64 * 264 * 2];  // 33792 B
  _Float16* As = (_Float16*)smem;  // [row][k], stride 136 halfs (17408 B used)
  __half* Co = (__half*)smem;      // alias after K-loop, 64 x 264

  const int t = threadIdx.x;
  const int lane = t & 63;
  const int w = t >> 6;
  const int l16 = lane & 15;
  const int q = lane >> 4;
  const int row0 = blockIdx.x * 64;

  // ---- staging: load i covers flat float idx t*4 + i*1024 (wave-contiguous)
  {
    const int r_base = t >> 5;       // 0..7
    const int col = (t & 31) * 4;    // 0..124
#pragma unroll
    for (int i = 0; i < 8; ++i) {
      int grow = row0 + r_base + i * 8;
      if (grow >= NNODES) grow = NNODES - 1;
      const floatx4 v = __builtin_nontemporal_load(
          (const floatx4*)(emb + (size_t)grow * HID + col));
      f16x4 h;
      h[0] = (_Float16)v.x; h[1] = (_Float16)v.y;
      h[2] = (_Float16)v.z; h[3] = (_Float16)v.w;
      *(f16x4*)&As[(r_base + i * 8) * 136 + col] = h;
    }
  }
  __syncthreads();

  floatx4 acc[4][4] = {};  // [rt][ct]
#pragma unroll
  for (int ks = 0; ks < 4; ++ks) {
    f16x8 bh[4];
#pragma unroll
    for (int ct = 0; ct < 4; ++ct) {
      const size_t idx = (size_t)(((w * 4 + ct) * 4 + ks) * 64 + lane) * 8;
      bh[ct] = *(const f16x8*)(Bf + idx);
    }
    f16x8 ah[4];
#pragma unroll
    for (int rt = 0; rt < 4; ++rt)
      ah[rt] = *(const f16x8*)&As[(rt * 16 + l16) * 136 + ks * 32 + q * 8];
#pragma unroll
    for (int rt = 0; rt < 4; ++rt)
#pragma unroll
      for (int ct = 0; ct < 4; ++ct)
        acc[rt][ct] = __builtin_amdgcn_mfma_f32_16x16x32_f16(ah[rt], bh[ct], acc[rt][ct], 0, 0, 0);
  }

  // epilogue: C/D layout col=lane&15, row=(lane>>4)*4+reg -> LDS (f16).
  __syncthreads();  // As reads done; safe to alias Co
#pragma unroll
  for (int rt = 0; rt < 4; ++rt)
#pragma unroll
    for (int ct = 0; ct < 4; ++ct)
#pragma unroll
      for (int r = 0; r < 4; ++r) {
        const int row = rt * 16 + q * 4 + r;
        const int col = w * 64 + ct * 16 + l16;
        Co[row * 264 + col] = __float2half(acc[rt][ct][r]);
      }
  __syncthreads();
  // quantize + store: 64 rows x 16 chunks of 16 channels. The 8 threads
  // covering one (row, half) are lanes [8a..8a+7] -> shfl_xor 1/2/4 max.
#pragma unroll
  for (int i = 0; i < 4; ++i) {
    const int chunk = t + i * 256;
    const int row = chunk >> 4;    // 0..63
    const int cx = chunk & 15;     // 0..15 (16B chunk within row)
    const int half = cx >> 3;      // 0 = src-proj cols, 1 = tgt-proj cols
    const f16x8 v0 = *(const f16x8*)&Co[row * 264 + cx * 16];
    const f16x8 v1 = *(const f16x8*)&Co[row * 264 + cx * 16 + 8];
    float f[16];
#pragma unroll
    for (int k = 0; k < 8; ++k) { f[k] = (float)v0[k]; f[8 + k] = (float)v1[k]; }
    float m = 0.f;
#pragma unroll
    for (int k = 0; k < 16; ++k) m = fmaxf(m, fabsf(f[k]));
    m = fmaxf(m, __shfl_xor(m, 1, 64));
    m = fmaxf(m, __shfl_xor(m, 2, 64));
    m = fmaxf(m, __shfl_xor(m, 4, 64));
    m = fmaxf(m, 1e-20f);
    const float qs = 127.0f / m;
    const int grow = row0 + row;
    if (grow < NNODES) {
      if ((cx & 7) == 0) scalesInv[2 * grow + half] = m * (1.0f / 127.0f);
      unsigned d[4];
#pragma unroll
      for (int dw = 0; dw < 4; ++dw) {
        unsigned acc_b = 0;
#pragma unroll
        for (int b = 0; b < 4; ++b) {
          int qv = (int)rintf(f[dw * 4 + b] * qs) + 128;
          qv = qv < 0 ? 0 : (qv > 255 ? 255 : qv);
          acc_b |= ((unsigned)qv) << (8 * b);
        }
        d[dw] = acc_b;
      }
      uint4 o; o.x = d[0]; o.y = d[1]; o.z = d[2]; o.w = d[3];
      *(uint4*)(P + (size_t)grow * 256 + cx * 16) = o;
    }
  }
}

// ---------------- Kernel 2: per-edge MLP + exp + fused partial-sum ---------
// Exact-fit grid: 15625 blocks x 4 waves x 16 edges = 1,000,000.
// 16 lanes/edge, 8 channels/lane, gather = 8 B/lane (dwordx2) = one 128 B
// line per endpoint. Dequant via v_perm: byte b -> f16 bits 0x6400|b
// (= 1024+b exact), minus 1152 gives (b-128) exact; then packed-f16
// fma/max + v_dot2_f32_f16. Per-wave sum -> atomicAdd into one of 64
// contention-spread slots (64 B apart) -> no reduce kernel.
__global__ __launch_bounds__(256) void edge_kernel(
    const uint8_t* __restrict__ P, const float* __restrict__ scalesInv,
    const int* __restrict__ lm,
    const float* __restrict__ b1, const float* __restrict__ W2,
    const float* __restrict__ b2, float* __restrict__ explog,
    float* __restrict__ accum) {
  const int lane = threadIdx.x & 63;
  const int wid = threadIdx.x >> 6;
  const int g = lane >> 4;    // edge sub-group 0..3
  const int l16 = lane & 15;
  const int c = l16 * 8;      // 8 channels per lane (== byte offset into half)

  f16x2 b1h[4], w2h[4];
  {
    const floatx4 b1a = *(const floatx4*)(b1 + c);
    const floatx4 b1b = *(const floatx4*)(b1 + c + 4);
    const floatx4 w2a = *(const floatx4*)(W2 + c);
    const floatx4 w2b = *(const floatx4*)(W2 + c + 4);
    b1h[0] = f16x2{(_Float16)b1a.x, (_Float16)b1a.y};
    b1h[1] = f16x2{(_Float16)b1a.z, (_Float16)b1a.w};
    b1h[2] = f16x2{(_Float16)b1b.x, (_Float16)b1b.y};
    b1h[3] = f16x2{(_Float16)b1b.z, (_Float16)b1b.w};
    w2h[0] = f16x2{(_Float16)w2a.x, (_Float16)w2a.y};
    w2h[1] = f16x2{(_Float16)w2a.z, (_Float16)w2a.w};
    w2h[2] = f16x2{(_Float16)w2b.x, (_Float16)w2b.y};
    w2h[3] = f16x2{(_Float16)w2b.z, (_Float16)w2b.w};
  }
  const f16x2 z2 = {(_Float16)0.f, (_Float16)0.f};
  const f16x2 kneg = {(_Float16)(-1152.f), (_Float16)(-1152.f)};
  const float b2v = b2[0];

  const int e0 = (blockIdx.x * 4 + wid) * 16;

  uint2 rs[4], rt_[4];
  float ssv[4], stv[4];
#pragma unroll
  for (int j = 0; j < 4; ++j) {
    const int ej = e0 + j * 4 + g;
    const int src = __builtin_nontemporal_load(lm + ej);
    const int tgt = __builtin_nontemporal_load(lm + NEDGES + ej);
    rs[j]  = *(const uint2*)(P + (size_t)src * 256 + c);
    rt_[j] = *(const uint2*)(P + (size_t)tgt * 256 + 128 + c);
    ssv[j] = scalesInv[2 * src];
    stv[j] = scalesInv[2 * tgt + 1];
  }
  float pe = 0.f;  // this lane's edge logit (valid when l16 < 4)
#pragma unroll
  for (int j = 0; j < 4; ++j) {
    const f16x2 si2 = __builtin_bit_cast(f16x2, __builtin_amdgcn_cvt_pkrtz(ssv[j], ssv[j]));
    const f16x2 ti2 = __builtin_bit_cast(f16x2, __builtin_amdgcn_cvt_pkrtz(stv[j], stv[j]));
    float p = 0.f;
    const unsigned su[2] = {rs[j].x, rs[j].y};
    const unsigned tu[2] = {rt_[j].x, rt_[j].y};
#pragma unroll
    for (int pr = 0; pr < 4; ++pr) {
      const unsigned w = pr >> 1;
      const unsigned sel = (pr & 1) ? 0x00070006u : 0x00050004u;
      const f16x2 hs = __builtin_bit_cast(f16x2, __builtin_amdgcn_perm(su[w], 0x64646464u, sel));
      const f16x2 ht = __builtin_bit_cast(f16x2, __builtin_amdgcn_perm(tu[w], 0x64646464u, sel));
      const f16x2 ds = hs + kneg;   // = u_s - 128, exact
      const f16x2 dt = ht + kneg;   // = u_t - 128, exact
      const f16x2 a = __builtin_elementwise_max(ds * si2 + (dt * ti2 + b1h[pr]), z2);
      p = __builtin_amdgcn_fdot2(a, w2h[pr], p, false);
    }
    p += __shfl_xor(p, 8, 64);
    p += __shfl_xor(p, 4, 64);
    p += __shfl_xor(p, 2, 64);
    p += __shfl_xor(p, 1, 64);
    pe = (l16 == j) ? p : pe;  // cndmask, no branch
  }

  float lsum = 0.f;
  if (l16 < 4) {  // single exp region: 16 lanes hold the wave's 16 edges
    const float ev = __expf(pe + b2v);
    explog[e0 + l16 * 4 + g] = ev;   // plain store: stays L2-resident for norm
    lsum = ev;
  }

#pragma unroll
  for (int off = 32; off >= 1; off >>= 1) lsum += __shfl_xor(lsum, off, 64);
  if (lane == 0)
    atomicAdd(accum + (((blockIdx.x << 2) + wid) & 63) * 16, lsum);
}

// ---------------- Kernel 3: normalize (sums the 64 slots per wave) ---------
__global__ __launch_bounds__(256) void norm_kernel(
    const float* __restrict__ explog, const float* __restrict__ accum,
    float* __restrict__ out) {
  float s = accum[(threadIdx.x & 63) * 16];
#pragma unroll
  for (int off = 32; off >= 1; off >>= 1) s += __shfl_xor(s, off, 64);
  const float inv = 1.0f / s;
  const int i = (blockIdx.x * 256 + threadIdx.x) * 4;
  if (i < NEDGES) {
    floatx4 v = *(const floatx4*)(explog + i);
    v.x *= inv; v.y *= inv; v.z *= inv; v.w *= inv;
    __builtin_nontemporal_store(v, (floatx4*)(out + i));
  }
}

extern "C" void kernel_launch(void* const* d_in, const int* in_sizes, int n_in,
                              void* d_out, int out_size, void* d_ws, size_t ws_size,
                              hipStream_t stream) {
  const float* emb = (const float*)d_in[0];
  const int*   lm  = (const int*)d_in[1];   // [2, 1M]: sources then targets
  const float* W1  = (const float*)d_in[2];
  const float* b1  = (const float*)d_in[3];
  const float* W2  = (const float*)d_in[4];
  const float* b2  = (const float*)d_in[5];
  float* out = (float*)d_out;

  char* ws = (char*)d_ws;
  uint8_t* P       = (uint8_t*)ws;                 // 25,600,000 B (uint8 biased)
  float* accum     = (float*)(ws + 25600000);      // 4,096 B (64 slots, 64 B apart)
  float* explog    = (float*)(ws + 25604096);      // 4,000,000 B
  _Float16* Bf     = (_Float16*)(ws + 29604096);   // 65,536 B
  float* scalesInv = (float*)(ws + 29669632);      // 800,000 B -> ends 30,469,632

  pack_b_kernel<<<16, 256, 0, stream>>>(W1, Bf, accum);
  project_kernel<<<1563, 256, 0, stream>>>(emb, Bf, P, scalesInv);
  edge_kernel<<<NEBLOCKS, 256, 0, stream>>>(P, scalesInv, lm, b1, W2, b2, explog, accum);
  norm_kernel<<<977, 256, 0, stream>>>(explog, accum, out);
}

// Round 5
// 154.098 us; speedup vs baseline: 1.0375x; 1.0375x over previous
//
#include <hip/hip_runtime.h>
#include <hip/hip_bf16.h>
#include <hip/hip_fp16.h>
#include <stdint.h>
#include <math.h>

#define NNODES 100000
#define HID 128
#define NEDGES 1000000
#define NEBLOCKS 7813  // edge blocks: 7813 * 4 waves * 32 edges >= 1,000,000 (tail-guarded)

typedef __attribute__((ext_vector_type(4))) float floatx4;
typedef _Float16 f16x2 __attribute__((ext_vector_type(2)));
typedef _Float16 f16x4 __attribute__((ext_vector_type(4)));
typedef _Float16 f16x8 __attribute__((ext_vector_type(8)));

// ---------------- Kernel 0: pack B = [W1_top | W1_bot] into MFMA fragment
// order, f16. Fragment: B[k=(lane>>4)*8+j][n=lane&15],
// element base ((ct*4+ks)*64+lane)*8, ct=0..15 (16-col tiles), ks=0..3.
// Also zeroes the 64 edge-sum accumulator slots (runs first each iteration).
__global__ __launch_bounds__(256) void pack_b_kernel(
    const float* __restrict__ W1, _Float16* __restrict__ Bf,
    float* __restrict__ accum) {
  if (blockIdx.x == 0 && threadIdx.x < 64) accum[threadIdx.x * 16] = 0.f;
  const int t = blockIdx.x * 256 + threadIdx.x;  // 0..4095
  const int lane = t & 63;
  const int ks = (t >> 6) & 3;
  const int ct = t >> 8;
  const int n = ct * 16 + (lane & 15);
  const int kb = ks * 32 + ((lane >> 4) * 8);
  f16x8 h;
#pragma unroll
  for (int j = 0; j < 8; ++j) {
    const int k = kb + j;
    const float v = (n < HID) ? W1[(size_t)k * HID + n]
                              : W1[(size_t)(HID + k) * HID + (n - HID)];
    h[j] = (_Float16)v;
  }
  *(f16x8*)(Bf + (size_t)t * 8) = h;
}

// ---------------- Kernel 1: node projection via single-pass f16 MFMA -------
// Block: 64 rows x 256 cols. Staging: fully-coalesced flat copy (nt loads:
// emb is dead after this read; keep it out of L2 so P writes stay resident
// for the edge kernel), in-register fp32->f16, LDS As[row][k] stride 136
// halfs. One barrier, K-loop: A via ds_read_b128, B frags from L2-hot packed
// global, 64 MFMA/wave. Co aliases As for the epilogue. Epilogue quantizes
// each 128-ch half-row to biased uint8 with a per-half linear scale
// (max|v|/127), storing P (1 B/ch) and scalesInv[node][half].
__global__ __launch_bounds__(256) void project_kernel(
    const float* __restrict__ emb, const _Float16* __restrict__ Bf,
    uint8_t* __restrict__ P, float* __restrict__ scalesInv) {
  __shared__ __align__(16) char smem[64 * 264 * 2];  // 33792 B
  _Float16* As = (_Float16*)smem;  // [row][k], stride 136 halfs (17408 B used)
  __half* Co = (__half*)smem;      // alias after K-loop, 64 x 264

  const int t = threadIdx.x;
  const int lane = t & 63;
  const int w = t >> 6;
  const int l16 = lane & 15;
  const int q = lane >> 4;
  const int row0 = blockIdx.x * 64;

  // ---- staging: load i covers flat float idx t*4 + i*1024 (wave-contiguous)
  {
    const int r_base = t >> 5;       // 0..7
    const int col = (t & 31) * 4;    // 0..124
#pragma unroll
    for (int i = 0; i < 8; ++i) {
      int grow = row0 + r_base + i * 8;
      if (grow >= NNODES) grow = NNODES - 1;
      const floatx4 v = __builtin_nontemporal_load(
          (const floatx4*)(emb + (size_t)grow * HID + col));
      f16x4 h;
      h[0] = (_Float16)v.x; h[1] = (_Float16)v.y;
      h[2] = (_Float16)v.z; h[3] = (_Float16)v.w;
      *(f16x4*)&As[(r_base + i * 8) * 136 + col] = h;
    }
  }
  __syncthreads();

  floatx4 acc[4][4] = {};  // [rt][ct]
#pragma unroll
  for (int ks = 0; ks < 4; ++ks) {
    f16x8 bh[4];
#pragma unroll
    for (int ct = 0; ct < 4; ++ct) {
      const size_t idx = (size_t)(((w * 4 + ct) * 4 + ks) * 64 + lane) * 8;
      bh[ct] = *(const f16x8*)(Bf + idx);
    }
    f16x8 ah[4];
#pragma unroll
    for (int rt = 0; rt < 4; ++rt)
      ah[rt] = *(const f16x8*)&As[(rt * 16 + l16) * 136 + ks * 32 + q * 8];
#pragma unroll
    for (int rt = 0; rt < 4; ++rt)
#pragma unroll
      for (int ct = 0; ct < 4; ++ct)
        acc[rt][ct] = __builtin_amdgcn_mfma_f32_16x16x32_f16(ah[rt], bh[ct], acc[rt][ct], 0, 0, 0);
  }

  // epilogue: C/D layout col=lane&15, row=(lane>>4)*4+reg -> LDS (f16).
  __syncthreads();  // As reads done; safe to alias Co
#pragma unroll
  for (int rt = 0; rt < 4; ++rt)
#pragma unroll
    for (int ct = 0; ct < 4; ++ct)
#pragma unroll
      for (int r = 0; r < 4; ++r) {
        const int row = rt * 16 + q * 4 + r;
        const int col = w * 64 + ct * 16 + l16;
        Co[row * 264 + col] = __float2half(acc[rt][ct][r]);
      }
  __syncthreads();
  // quantize + store: 64 rows x 16 chunks of 16 channels. The 8 threads
  // covering one (row, half) are lanes [8a..8a+7] -> shfl_xor 1/2/4 max.
#pragma unroll
  for (int i = 0; i < 4; ++i) {
    const int chunk = t + i * 256;
    const int row = chunk >> 4;    // 0..63
    const int cx = chunk & 15;     // 0..15 (16B chunk within row)
    const int half = cx >> 3;      // 0 = src-proj cols, 1 = tgt-proj cols
    const f16x8 v0 = *(const f16x8*)&Co[row * 264 + cx * 16];
    const f16x8 v1 = *(const f16x8*)&Co[row * 264 + cx * 16 + 8];
    float f[16];
#pragma unroll
    for (int k = 0; k < 8; ++k) { f[k] = (float)v0[k]; f[8 + k] = (float)v1[k]; }
    float m = 0.f;
#pragma unroll
    for (int k = 0; k < 16; ++k) m = fmaxf(m, fabsf(f[k]));
    m = fmaxf(m, __shfl_xor(m, 1, 64));
    m = fmaxf(m, __shfl_xor(m, 2, 64));
    m = fmaxf(m, __shfl_xor(m, 4, 64));
    m = fmaxf(m, 1e-20f);
    const float qs = 127.0f / m;
    const int grow = row0 + row;
    if (grow < NNODES) {
      if ((cx & 7) == 0) scalesInv[2 * grow + half] = m * (1.0f / 127.0f);
      unsigned d[4];
#pragma unroll
      for (int dw = 0; dw < 4; ++dw) {
        unsigned acc_b = 0;
#pragma unroll
        for (int b = 0; b < 4; ++b) {
          int qv = (int)rintf(f[dw * 4 + b] * qs) + 128;
          qv = qv < 0 ? 0 : (qv > 255 ? 255 : qv);
          acc_b |= ((unsigned)qv) << (8 * b);
        }
        d[dw] = acc_b;
      }
      uint4 o; o.x = d[0]; o.y = d[1]; o.z = d[2]; o.w = d[3];
      *(uint4*)(P + (size_t)grow * 256 + cx * 16) = o;
    }
  }
}

// ---------------- Kernel 2: per-edge MLP + exp + fused partial-sum ---------
// Grid: 7813 blocks x 4 waves x 32 edges (tail-guarded). 16 lanes/edge,
// 8 channels/lane, gather = 8 B/lane (dwordx2) = one 128 B line per
// endpoint; 16 gathers in flight per wave. Dequant via v_perm: byte b ->
// f16 bits 0x6400|b (= 1024+b exact), minus 1152 gives (b-128) exact; then
// packed-f16 fma/max + v_dot2_f32_f16. Per-wave sums -> LDS -> ONE
// atomicAdd per block into one of 64 contention-spread slots.
__global__ __launch_bounds__(256) void edge_kernel(
    const uint8_t* __restrict__ P, const float* __restrict__ scalesInv,
    const int* __restrict__ lm,
    const float* __restrict__ b1, const float* __restrict__ W2,
    const float* __restrict__ b2, float* __restrict__ explog,
    float* __restrict__ accum) {
  const int lane = threadIdx.x & 63;
  const int wid = threadIdx.x >> 6;
  const int g = lane >> 4;    // edge sub-group 0..3
  const int l16 = lane & 15;
  const int c = l16 * 8;      // 8 channels per lane (== byte offset into half)

  f16x2 b1h[4], w2h[4];
  {
    const floatx4 b1a = *(const floatx4*)(b1 + c);
    const floatx4 b1b = *(const floatx4*)(b1 + c + 4);
    const floatx4 w2a = *(const floatx4*)(W2 + c);
    const floatx4 w2b = *(const floatx4*)(W2 + c + 4);
    b1h[0] = f16x2{(_Float16)b1a.x, (_Float16)b1a.y};
    b1h[1] = f16x2{(_Float16)b1a.z, (_Float16)b1a.w};
    b1h[2] = f16x2{(_Float16)b1b.x, (_Float16)b1b.y};
    b1h[3] = f16x2{(_Float16)b1b.z, (_Float16)b1b.w};
    w2h[0] = f16x2{(_Float16)w2a.x, (_Float16)w2a.y};
    w2h[1] = f16x2{(_Float16)w2a.z, (_Float16)w2a.w};
    w2h[2] = f16x2{(_Float16)w2b.x, (_Float16)w2b.y};
    w2h[3] = f16x2{(_Float16)w2b.z, (_Float16)w2b.w};
  }
  const f16x2 z2 = {(_Float16)0.f, (_Float16)0.f};
  const f16x2 kneg = {(_Float16)(-1152.f), (_Float16)(-1152.f)};
  const float b2v = b2[0];

  const int e0 = (blockIdx.x * 4 + wid) * 32;

  uint2 rs[8], rt_[8];
  float ssv[8], stv[8];
#pragma unroll
  for (int j = 0; j < 8; ++j) {
    int ej = e0 + j * 4 + g;
    ej = ej < NEDGES ? ej : (NEDGES - 1);  // tail clamp (last block only)
    const int src = lm[ej];
    const int tgt = lm[NEDGES + ej];
    rs[j]  = *(const uint2*)(P + (size_t)src * 256 + c);
    rt_[j] = *(const uint2*)(P + (size_t)tgt * 256 + 128 + c);
    ssv[j] = scalesInv[2 * src];
    stv[j] = scalesInv[2 * tgt + 1];
  }
  float pe = 0.f;  // this lane's edge logit (valid when l16 < 8)
#pragma unroll
  for (int j = 0; j < 8; ++j) {
    const f16x2 si2 = __builtin_bit_cast(f16x2, __builtin_amdgcn_cvt_pkrtz(ssv[j], ssv[j]));
    const f16x2 ti2 = __builtin_bit_cast(f16x2, __builtin_amdgcn_cvt_pkrtz(stv[j], stv[j]));
    float p = 0.f;
    const unsigned su[2] = {rs[j].x, rs[j].y};
    const unsigned tu[2] = {rt_[j].x, rt_[j].y};
#pragma unroll
    for (int pr = 0; pr < 4; ++pr) {
      const unsigned w = pr >> 1;
      const unsigned sel = (pr & 1) ? 0x00070006u : 0x00050004u;
      const f16x2 hs = __builtin_bit_cast(f16x2, __builtin_amdgcn_perm(su[w], 0x64646464u, sel));
      const f16x2 ht = __builtin_bit_cast(f16x2, __builtin_amdgcn_perm(tu[w], 0x64646464u, sel));
      const f16x2 ds = hs + kneg;   // = u_s - 128, exact
      const f16x2 dt = ht + kneg;   // = u_t - 128, exact
      const f16x2 a = __builtin_elementwise_max(ds * si2 + (dt * ti2 + b1h[pr]), z2);
      p = __builtin_amdgcn_fdot2(a, w2h[pr], p, false);
    }
    p += __shfl_xor(p, 8, 64);
    p += __shfl_xor(p, 4, 64);
    p += __shfl_xor(p, 2, 64);
    p += __shfl_xor(p, 1, 64);
    pe = (l16 == j) ? p : pe;  // cndmask, no branch
  }

  float lsum = 0.f;
  if (l16 < 8) {  // single exp region: 32 lanes hold the wave's 32 edges
    const int idx = e0 + l16 * 4 + g;
    if (idx < NEDGES) {
      const float ev = __expf(pe + b2v);
      explog[idx] = ev;   // plain store: stays L2-resident for norm
      lsum = ev;
    }
  }

#pragma unroll
  for (int off = 32; off >= 1; off >>= 1) lsum += __shfl_xor(lsum, off, 64);
  __shared__ float wsums[4];
  if (lane == 0) wsums[wid] = lsum;
  __syncthreads();
  if (threadIdx.x == 0)
    atomicAdd(accum + (blockIdx.x & 63) * 16,
              wsums[0] + wsums[1] + wsums[2] + wsums[3]);
}

// ---------------- Kernel 3: normalize (sums the 64 slots per wave) ---------
__global__ __launch_bounds__(256) void norm_kernel(
    const float* __restrict__ explog, const float* __restrict__ accum,
    float* __restrict__ out) {
  float s = accum[(threadIdx.x & 63) * 16];
#pragma unroll
  for (int off = 32; off >= 1; off >>= 1) s += __shfl_xor(s, off, 64);
  const float inv = 1.0f / s;
  const int i = (blockIdx.x * 256 + threadIdx.x) * 4;
  if (i < NEDGES) {
    floatx4 v = *(const floatx4*)(explog + i);
    v.x *= inv; v.y *= inv; v.z *= inv; v.w *= inv;
    __builtin_nontemporal_store(v, (floatx4*)(out + i));
  }
}

extern "C" void kernel_launch(void* const* d_in, const int* in_sizes, int n_in,
                              void* d_out, int out_size, void* d_ws, size_t ws_size,
                              hipStream_t stream) {
  const float* emb = (const float*)d_in[0];
  const int*   lm  = (const int*)d_in[1];   // [2, 1M]: sources then targets
  const float* W1  = (const float*)d_in[2];
  const float* b1  = (const float*)d_in[3];
  const float* W2  = (const float*)d_in[4];
  const float* b2  = (const float*)d_in[5];
  float* out = (float*)d_out;

  char* ws = (char*)d_ws;
  uint8_t* P       = (uint8_t*)ws;                 // 25,600,000 B (uint8 biased)
  float* accum     = (float*)(ws + 25600000);      // 4,096 B (64 slots, 64 B apart)
  float* explog    = (float*)(ws + 25604096);      // 4,000,000 B
  _Float16* Bf     = (_Float16*)(ws + 29604096);   // 65,536 B
  float* scalesInv = (float*)(ws + 29669632);      // 800,000 B -> ends 30,469,632

  pack_b_kernel<<<16, 256, 0, stream>>>(W1, Bf, accum);
  project_kernel<<<1563, 256, 0, stream>>>(emb, Bf, P, scalesInv);
  edge_kernel<<<NEBLOCKS, 256, 0, stream>>>(P, scalesInv, lm, b1, W2, b2, explog, accum);
  norm_kernel<<<977, 256, 0, stream>>>(explog, accum, out);
}